// Round 11
// baseline (974.292 us; speedup 1.0000x reference)
//
#include <hip/hip_runtime.h>

#define B_ROWS 32768
#define KCODES 4096

typedef float f32x4 __attribute__((ext_vector_type(4)));
typedef _Float16 f16x8 __attribute__((ext_vector_type(8)));
typedef _Float16 f16x4 __attribute__((ext_vector_type(4)));

struct Split { _Float16 h, m; };

// split f32 -> fp16 head + fp16 scaled residual (residual x256 stays normal;
// C = hi + mid/256 recombines to f32-grade accuracy)
__device__ __forceinline__ Split split2(float v)
{
  Split s;
  s.h = (_Float16)v;
  s.m = (_Float16)((v - (float)s.h) * 256.f);
  return s;
}

// ---------------------------------------------------------------------------
// fp16-split MFMA GEMM with 2-DEEP register prefetch (T14 extended):
//   prologue: gload(0)->set0, gload(1)->set1
//   step t:   lstore(set) ; barrier ; gload(t+2)->set ; MFMA(t) ; barrier
// Loads get ~2 k-steps (~800 cyc) to land -> HBM latency covered (round-10's
// 1-deep left ~550 cyc exposed -> 1 TB/s effective).
// Block tile 128x64, 4 waves of 64x32, BK=32, single-buffer LDS (30KB).
// XCD swizzle: flat -> xcd=flat&7, s=flat>>3, nb=s%nbx, mb=(s/nbx)*8+xcd.
// SPLITA=true : A f32 [M][K], split in the write phase (K-tail guarded).
// SPLITA=false: A pre-split fp16 pair, row stride Astr halves.
// hi += A1B1 ; mid += A1*B2s + A2s*B1 ; C = hi + mid*2^-8 + bias.
// Two NAMED register sets (no runtime-indexed reg arrays -> no scratch).
// ---------------------------------------------------------------------------
template<bool SPLITA>
__global__ __launch_bounds__(256, 3)
void hgemm(const float* __restrict__ Af, const _Float16* __restrict__ Ah,
           const _Float16* __restrict__ Am, int Astr,
           const _Float16* __restrict__ Bh, const _Float16* __restrict__ Bm,
           const float* __restrict__ bias, float* __restrict__ C,
           int M, int N, int K, int Kp, int nbx)
{
  __shared__ _Float16 As1[128 * 40];
  __shared__ _Float16 As2[128 * 40];
  __shared__ _Float16 Bs1[64 * 40];
  __shared__ _Float16 Bs2[64 * 40];

  const int flat = blockIdx.x;
  const int s_   = flat >> 3;
  const int mb   = (s_ / nbx) * 8 + (flat & 7);
  const int nb   = s_ % nbx;
  const int m0   = mb * 128;
  const int n0   = nb * 64;

  const int tid  = threadIdx.x;
  const int lane = tid & 63;
  const int wid  = tid >> 6;
  const int l15  = lane & 15;
  const int lg   = lane >> 4;
  const int wm   = (wid >> 1) * 64;
  const int wn   = (wid & 1) * 32;

  f32x4 hi[4][2], mid[4][2];
  #pragma unroll
  for (int i = 0; i < 4; ++i)
    #pragma unroll
    for (int j = 0; j < 2; ++j) { hi[i][j] = (f32x4)0.f; mid[i][j] = (f32x4)0.f; }

  const int far = tid >> 2;           // f32-A stage: row 0..63 (+64)
  const int fak = (tid & 3) << 3;     // 0,8,16,24
  const int sar = tid >> 1;           // pre-split A stage: row 0..127
  const int sak = (tid & 1) << 4;     // 0/16 halves
  const int sbn = tid >> 2;           // B stage: 0..63
  const int sbk = (tid & 3) << 3;     // 0,8,16,24 halves

  // two named staging sets (2-deep pipeline)
  float4 vaA[2][2], vaB[2][2];
  uint4 raA0, raA1, raA2, raA3, raB0, raB1, raB2, raB3;
  uint4 rbA0, rbA1, rbB0, rbB1;

  auto gloadA = [&](int k0) {
    if (SPLITA) {
      #pragma unroll
      for (int p = 0; p < 2; ++p) {
        const int r = far + (p << 6);
        const int c = k0 + fak;
        const float* src = Af + (size_t)(m0 + r) * K + c;
        vaA[p][0] = (c < K)     ? *reinterpret_cast<const float4*>(src)
                                : make_float4(0.f, 0.f, 0.f, 0.f);
        vaA[p][1] = (c + 4 < K) ? *reinterpret_cast<const float4*>(src + 4)
                                : make_float4(0.f, 0.f, 0.f, 0.f);
      }
    } else {
      const size_t gA = (size_t)(m0 + sar) * Astr + k0 + sak;
      raA0 = *reinterpret_cast<const uint4*>(Ah + gA);
      raA1 = *reinterpret_cast<const uint4*>(Ah + gA + 8);
      raA2 = *reinterpret_cast<const uint4*>(Am + gA);
      raA3 = *reinterpret_cast<const uint4*>(Am + gA + 8);
    }
    const size_t gB = (size_t)(n0 + sbn) * Kp + k0 + sbk;
    rbA0 = *reinterpret_cast<const uint4*>(Bh + gB);
    rbA1 = *reinterpret_cast<const uint4*>(Bm + gB);
  };
  auto gloadB = [&](int k0) {
    if (SPLITA) {
      #pragma unroll
      for (int p = 0; p < 2; ++p) {
        const int r = far + (p << 6);
        const int c = k0 + fak;
        const float* src = Af + (size_t)(m0 + r) * K + c;
        vaB[p][0] = (c < K)     ? *reinterpret_cast<const float4*>(src)
                                : make_float4(0.f, 0.f, 0.f, 0.f);
        vaB[p][1] = (c + 4 < K) ? *reinterpret_cast<const float4*>(src + 4)
                                : make_float4(0.f, 0.f, 0.f, 0.f);
      }
    } else {
      const size_t gA = (size_t)(m0 + sar) * Astr + k0 + sak;
      raB0 = *reinterpret_cast<const uint4*>(Ah + gA);
      raB1 = *reinterpret_cast<const uint4*>(Ah + gA + 8);
      raB2 = *reinterpret_cast<const uint4*>(Am + gA);
      raB3 = *reinterpret_cast<const uint4*>(Am + gA + 8);
    }
    const size_t gB = (size_t)(n0 + sbn) * Kp + k0 + sbk;
    rbB0 = *reinterpret_cast<const uint4*>(Bh + gB);
    rbB1 = *reinterpret_cast<const uint4*>(Bm + gB);
  };

  auto lstoreA = [&]() {
    if (SPLITA) {
      #pragma unroll
      for (int p = 0; p < 2; ++p) {
        const int r = far + (p << 6);
        const Split s0 = split2(vaA[p][0].x), s1 = split2(vaA[p][0].y),
                    s2 = split2(vaA[p][0].z), s3 = split2(vaA[p][0].w);
        const Split s4 = split2(vaA[p][1].x), s5 = split2(vaA[p][1].y),
                    s6 = split2(vaA[p][1].z), s7 = split2(vaA[p][1].w);
        f16x8 h, m;
        h[0]=s0.h; h[1]=s1.h; h[2]=s2.h; h[3]=s3.h; h[4]=s4.h; h[5]=s5.h; h[6]=s6.h; h[7]=s7.h;
        m[0]=s0.m; m[1]=s1.m; m[2]=s2.m; m[3]=s3.m; m[4]=s4.m; m[5]=s5.m; m[6]=s6.m; m[7]=s7.m;
        *reinterpret_cast<f16x8*>(&As1[r * 40 + fak]) = h;
        *reinterpret_cast<f16x8*>(&As2[r * 40 + fak]) = m;
      }
    } else {
      const int lA = sar * 40 + sak;
      *reinterpret_cast<uint4*>(&As1[lA])     = raA0;
      *reinterpret_cast<uint4*>(&As1[lA + 8]) = raA1;
      *reinterpret_cast<uint4*>(&As2[lA])     = raA2;
      *reinterpret_cast<uint4*>(&As2[lA + 8]) = raA3;
    }
    const int lB = sbn * 40 + sbk;
    *reinterpret_cast<uint4*>(&Bs1[lB]) = rbA0;
    *reinterpret_cast<uint4*>(&Bs2[lB]) = rbA1;
  };
  auto lstoreB = [&]() {
    if (SPLITA) {
      #pragma unroll
      for (int p = 0; p < 2; ++p) {
        const int r = far + (p << 6);
        const Split s0 = split2(vaB[p][0].x), s1 = split2(vaB[p][0].y),
                    s2 = split2(vaB[p][0].z), s3 = split2(vaB[p][0].w);
        const Split s4 = split2(vaB[p][1].x), s5 = split2(vaB[p][1].y),
                    s6 = split2(vaB[p][1].z), s7 = split2(vaB[p][1].w);
        f16x8 h, m;
        h[0]=s0.h; h[1]=s1.h; h[2]=s2.h; h[3]=s3.h; h[4]=s4.h; h[5]=s5.h; h[6]=s6.h; h[7]=s7.h;
        m[0]=s0.m; m[1]=s1.m; m[2]=s2.m; m[3]=s3.m; m[4]=s4.m; m[5]=s5.m; m[6]=s6.m; m[7]=s7.m;
        *reinterpret_cast<f16x8*>(&As1[r * 40 + fak]) = h;
        *reinterpret_cast<f16x8*>(&As2[r * 40 + fak]) = m;
      }
    } else {
      const int lA = sar * 40 + sak;
      *reinterpret_cast<uint4*>(&As1[lA])     = raB0;
      *reinterpret_cast<uint4*>(&As1[lA + 8]) = raB1;
      *reinterpret_cast<uint4*>(&As2[lA])     = raB2;
      *reinterpret_cast<uint4*>(&As2[lA + 8]) = raB3;
    }
    const int lB = sbn * 40 + sbk;
    *reinterpret_cast<uint4*>(&Bs1[lB]) = rbB0;
    *reinterpret_cast<uint4*>(&Bs2[lB]) = rbB1;
  };

  auto compute = [&]() {
    f16x8 a1[4], b[2];
    #pragma unroll
    for (int i = 0; i < 4; ++i)
      a1[i] = *reinterpret_cast<const f16x8*>(&As1[(wm + i * 16 + l15) * 40 + 8 * lg]);
    #pragma unroll
    for (int j = 0; j < 2; ++j)
      b[j] = *reinterpret_cast<const f16x8*>(&Bs1[(wn + j * 16 + l15) * 40 + 8 * lg]);
    #pragma unroll
    for (int i = 0; i < 4; ++i)
      #pragma unroll
      for (int j = 0; j < 2; ++j)
        hi[i][j] = __builtin_amdgcn_mfma_f32_16x16x32_f16(a1[i], b[j], hi[i][j], 0, 0, 0);
    #pragma unroll
    for (int i = 0; i < 4; ++i) {
      const f16x8 a2 = *reinterpret_cast<const f16x8*>(&As2[(wm + i * 16 + l15) * 40 + 8 * lg]);
      #pragma unroll
      for (int j = 0; j < 2; ++j)
        mid[i][j] = __builtin_amdgcn_mfma_f32_16x16x32_f16(a2, b[j], mid[i][j], 0, 0, 0);
    }
    #pragma unroll
    for (int j = 0; j < 2; ++j)
      b[j] = *reinterpret_cast<const f16x8*>(&Bs2[(wn + j * 16 + l15) * 40 + 8 * lg]);
    #pragma unroll
    for (int i = 0; i < 4; ++i)
      #pragma unroll
      for (int j = 0; j < 2; ++j)
        mid[i][j] = __builtin_amdgcn_mfma_f32_16x16x32_f16(a1[i], b[j], mid[i][j], 0, 0, 0);
  };

  const int nk = Kp >> 5;      // >= 4 for all our shapes
  gloadA(0);
  gloadB(1 << 5);
  int kt = 0;
  #pragma unroll 1
  while (kt + 2 <= nk) {
    // step kt (set A)
    lstoreA();
    __syncthreads();
    if (kt + 2 < nk) gloadA((kt + 2) << 5);
    compute();
    __syncthreads();
    // step kt+1 (set B)
    lstoreB();
    __syncthreads();
    if (kt + 3 < nk) gloadB((kt + 3) << 5);
    compute();
    __syncthreads();
    kt += 2;
  }
  if (kt < nk) {               // odd tail (set A holds tile kt)
    lstoreA();
    __syncthreads();
    compute();
    __syncthreads();
  }

  // epilogue: D row = 4*lg + r, col = l15 (m89-verified layout)
  #pragma unroll
  for (int i = 0; i < 4; ++i)
    #pragma unroll
    for (int j = 0; j < 2; ++j) {
      const int col = n0 + wn + j * 16 + l15;
      const float bs = bias[col];
      #pragma unroll
      for (int r = 0; r < 4; ++r) {
        const int row = m0 + wm + i * 16 + 4 * lg + r;
        C[(size_t)row * N + col] = hi[i][j][r] + 0.00390625f * mid[i][j][r] + bs;
      }
    }
}

// ---------------------------------------------------------------------------
// Row LayerNorm + exact GELU, writing split fp16 pair IN-PLACE over the f32
// row: halves [0..Wd) = head, [Wd..2Wd) = scaled residual. One block per row.
// ---------------------------------------------------------------------------
__global__ __launch_bounds__(256)
void ln_gelu_split(float* __restrict__ buf, const float* __restrict__ g,
                   const float* __restrict__ be, int Wd)
{
  __shared__ float rs[4], rs2[4];
  const int row = blockIdx.x;
  const int tid = threadIdx.x;
  float* x = buf + (size_t)row * Wd;
  const float v0 = x[tid];
  const float v1 = (Wd > 256) ? x[tid + 256] : 0.f;
  float s = v0 + v1, s2 = v0 * v0 + v1 * v1;
  #pragma unroll
  for (int m = 32; m; m >>= 1) { s += __shfl_down(s, m); s2 += __shfl_down(s2, m); }
  const int ln = tid & 63, wv = tid >> 6;
  if (ln == 0) { rs[wv] = s; rs2[wv] = s2; }
  __syncthreads();
  if (tid == 0) {
    const float S = rs[0] + rs[1] + rs[2] + rs[3];
    const float S2 = rs2[0] + rs2[1] + rs2[2] + rs2[3];
    const float mean = S / Wd;
    const float var = S2 / Wd - mean * mean;
    rs[0] = mean; rs2[0] = 1.0f / sqrtf(var + 1e-5f);
  }
  __syncthreads();
  const float mean = rs[0], inv = rs2[0];
  float y0 = (v0 - mean) * inv * g[tid] + be[tid];
  y0 = 0.5f * y0 * (1.f + erff(y0 * 0.70710678118654752f));
  float y1 = 0.f;
  if (Wd > 256) {
    y1 = (v1 - mean) * inv * g[tid + 256] + be[tid + 256];
    y1 = 0.5f * y1 * (1.f + erff(y1 * 0.70710678118654752f));
  }
  _Float16* hb = reinterpret_cast<_Float16*>(x);
  const Split s0 = split2(y0);
  hb[tid] = s0.h; hb[Wd + tid] = s0.m;
  if (Wd > 256) {
    const Split s1 = split2(y1);
    hb[tid + 256] = s1.h; hb[Wd + tid + 256] = s1.m;
  }
}

// ---------------------------------------------------------------------------
// VQ argmin (round-10 structure, passed): Z resident in LDS; flattened 32
// steps (8 chunks x 4 k-tiles); per step: E-write(t) -> barrier -> issue
// E-load(t+1) -> MFMA(t) -> barrier. E loads are L2-resident (1-deep covers).
// Grid 2048, XCD swizzle.
// ---------------------------------------------------------------------------
__global__ __launch_bounds__(256)
void vq_mfma(const float* __restrict__ Z, const _Float16* __restrict__ E1,
             const _Float16* __restrict__ E2, const float* __restrict__ e2,
             float* __restrict__ pval, int* __restrict__ pidx)
{
  __shared__ _Float16 Zs1[64 * 136];
  __shared__ _Float16 Zs2[64 * 136];
  __shared__ _Float16 Es1[128 * 40];
  __shared__ _Float16 Es2[128 * 40];

  const int flat = blockIdx.x;
  const int s_   = flat >> 3;
  const int mb   = (s_ >> 2) * 8 + (flat & 7);
  const int split = s_ & 3;
  const int m0   = mb * 64;

  const int tid  = threadIdx.x;
  const int lane = tid & 63;
  const int wid  = tid >> 6;
  const int l15  = lane & 15;
  const int lg   = lane >> 4;
  const int wn   = wid * 32;

  {
    const int zr = tid >> 2;
    #pragma unroll
    for (int q = 0; q < 8; ++q) {
      const int kk = ((tid & 3) << 2) + (q << 4);
      float4 v = *reinterpret_cast<const float4*>(Z + (size_t)(m0 + zr) * 128 + kk);
      const Split sx = split2(v.x), sy = split2(v.y), sz = split2(v.z), sw = split2(v.w);
      f16x4 h, m;
      h[0] = sx.h; h[1] = sy.h; h[2] = sz.h; h[3] = sw.h;
      m[0] = sx.m; m[1] = sy.m; m[2] = sz.m; m[3] = sw.m;
      *reinterpret_cast<f16x4*>(&Zs1[zr * 136 + kk]) = h;
      *reinterpret_cast<f16x4*>(&Zs2[zr * 136 + kk]) = m;
    }
  }

  float bv[16];
  int   bi[16];
  #pragma unroll
  for (int s = 0; s < 16; ++s) { bv[s] = 3.4e38f; bi[s] = 0x7fffffff; }

  const int sbn = tid >> 1;
  const int sbk = (tid & 1) << 4;
  const int lb  = sbn * 40 + sbk;

  uint4 re0, re1, re2, re3;
  auto eload = [&](int t) {                 // t = ch*4 + kt
    const int n0 = split * 1024 + (t >> 2) * 128;
    const int k0 = (t & 3) << 5;
    const size_t gb = (size_t)(n0 + sbn) * 128 + k0 + sbk;
    re0 = *reinterpret_cast<const uint4*>(E1 + gb);
    re1 = *reinterpret_cast<const uint4*>(E1 + gb + 8);
    re2 = *reinterpret_cast<const uint4*>(E2 + gb);
    re3 = *reinterpret_cast<const uint4*>(E2 + gb + 8);
  };

  f32x4 hi[4][2], mid[4][2];

  eload(0);
  #pragma unroll 1
  for (int t = 0; t < 32; ++t) {
    if ((t & 3) == 0) {
      #pragma unroll
      for (int i = 0; i < 4; ++i)
        #pragma unroll
        for (int j = 0; j < 2; ++j) { hi[i][j] = (f32x4)0.f; mid[i][j] = (f32x4)0.f; }
    }
    *reinterpret_cast<uint4*>(&Es1[lb])     = re0;
    *reinterpret_cast<uint4*>(&Es1[lb + 8]) = re1;
    *reinterpret_cast<uint4*>(&Es2[lb])     = re2;
    *reinterpret_cast<uint4*>(&Es2[lb + 8]) = re3;
    __syncthreads();
    if (t + 1 < 32) eload(t + 1);

    const int k0 = (t & 3) << 5;
    f16x8 a1[4], b[2];
    #pragma unroll
    for (int i = 0; i < 4; ++i)
      a1[i] = *reinterpret_cast<const f16x8*>(&Zs1[(i * 16 + l15) * 136 + k0 + 8 * lg]);
    #pragma unroll
    for (int j = 0; j < 2; ++j)
      b[j] = *reinterpret_cast<const f16x8*>(&Es1[(wn + j * 16 + l15) * 40 + 8 * lg]);
    #pragma unroll
    for (int i = 0; i < 4; ++i)
      #pragma unroll
      for (int j = 0; j < 2; ++j)
        hi[i][j] = __builtin_amdgcn_mfma_f32_16x16x32_f16(a1[i], b[j], hi[i][j], 0, 0, 0);
    #pragma unroll
    for (int i = 0; i < 4; ++i) {
      const f16x8 a2 = *reinterpret_cast<const f16x8*>(&Zs2[(i * 16 + l15) * 136 + k0 + 8 * lg]);
      #pragma unroll
      for (int j = 0; j < 2; ++j)
        mid[i][j] = __builtin_amdgcn_mfma_f32_16x16x32_f16(a2, b[j], mid[i][j], 0, 0, 0);
    }
    #pragma unroll
    for (int j = 0; j < 2; ++j)
      b[j] = *reinterpret_cast<const f16x8*>(&Es2[(wn + j * 16 + l15) * 40 + 8 * lg]);
    #pragma unroll
    for (int i = 0; i < 4; ++i)
      #pragma unroll
      for (int j = 0; j < 2; ++j)
        mid[i][j] = __builtin_amdgcn_mfma_f32_16x16x32_f16(a1[i], b[j], mid[i][j], 0, 0, 0);

    if ((t & 3) == 3) {
      const int n0 = split * 1024 + (t >> 2) * 128;
      #pragma unroll
      for (int j = 0; j < 2; ++j) {
        const int c = n0 + wn + j * 16 + l15;
        const float ec = e2[c];
        #pragma unroll
        for (int i = 0; i < 4; ++i)
          #pragma unroll
          for (int r = 0; r < 4; ++r) {
            const float sc = ec - 2.f * (hi[i][j][r] + 0.00390625f * mid[i][j][r]);
            if (sc < bv[i * 4 + r]) { bv[i * 4 + r] = sc; bi[i * 4 + r] = c; }
          }
      }
    }
    __syncthreads();
  }

  #pragma unroll
  for (int s = 0; s < 16; ++s) {
    float v = bv[s]; int ix = bi[s];
    #pragma unroll
    for (int m = 1; m < 16; m <<= 1) {
      const float ov = __shfl_xor(v, m);
      const int   oi = __shfl_xor(ix, m);
      if (ov < v || (ov == v && oi < ix)) { v = ov; ix = oi; }
    }
    if (l15 == 0) {
      const int row = m0 + (s >> 2) * 16 + 4 * lg + (s & 3);
      pval[(size_t)row * 16 + split * 4 + wid] = v;
      pidx[(size_t)row * 16 + split * 4 + wid] = ix;
    }
  }
}

// weight prep: W [K][N] f32 -> Bh/Bm [N][Kp] fp16 (transposed, zero-padded)
__global__ void prep_wT(const float* __restrict__ W, _Float16* __restrict__ Bh,
                        _Float16* __restrict__ Bm, int K, int N, int nshift,
                        int nmask, int Kp)
{
  const int i = blockIdx.x * 256 + threadIdx.x;
  if (i >= N * Kp) return;
  const int n = i & nmask;
  const int k = i >> nshift;
  const float v = (k < K) ? W[(size_t)k * N + n] : 0.f;
  const Split s = split2(v);
  Bh[(size_t)n * Kp + k] = s.h;
  Bm[(size_t)n * Kp + k] = s.m;
}

__global__ void prep_emb(const float* __restrict__ E, _Float16* __restrict__ E1,
                         _Float16* __restrict__ E2)
{
  const int i = blockIdx.x * 256 + threadIdx.x;
  const Split s = split2(E[i]);
  E1[i] = s.h; E2[i] = s.m;
}

__global__ void vq_reduce(const float* __restrict__ pval, const int* __restrict__ pidx,
                          int* __restrict__ idxout, float* __restrict__ idxf,
                          int* __restrict__ counts)
{
  const int b = blockIdx.x * 256 + threadIdx.x;
  if (b >= B_ROWS) return;
  float best = 3.4e38f; int bix = 0x7fffffff;
  #pragma unroll
  for (int j = 0; j < 16; ++j) {
    const float v = pval[(size_t)b * 16 + j];
    const int   ii = pidx[(size_t)b * 16 + j];
    if (v < best || (v == best && ii < bix)) { best = v; bix = ii; }
  }
  idxout[b] = bix;
  idxf[b] = (float)bix;
  atomicAdd(&counts[bix], 1);
}

__global__ __launch_bounds__(256)
void gather_commit(const int* __restrict__ idx, const float* __restrict__ E,
                   const float* __restrict__ ZE, float* __restrict__ ZQ,
                   float* __restrict__ cpart)
{
  __shared__ float red[4];
  const int b = blockIdx.x * 8 + (threadIdx.x >> 5);
  const int ch = threadIdx.x & 31;
  const int k = idx[b];
  float4 q = *reinterpret_cast<const float4*>(E + (size_t)k * 128 + ch * 4);
  float4 z = *reinterpret_cast<const float4*>(ZE + (size_t)b * 128 + ch * 4);
  *reinterpret_cast<float4*>(ZQ + (size_t)b * 128 + ch * 4) = q;
  float dx = q.x - z.x, dy = q.y - z.y, dz = q.z - z.z, dw = q.w - z.w;
  float s = dx * dx + dy * dy + dz * dz + dw * dw;
  #pragma unroll
  for (int m = 32; m; m >>= 1) s += __shfl_down(s, m);
  const int lane = threadIdx.x & 63, wv = threadIdx.x >> 6;
  if (lane == 0) red[wv] = s;
  __syncthreads();
  if (threadIdx.x == 0) cpart[blockIdx.x] = red[0] + red[1] + red[2] + red[3];
}

__global__ void e2_kernel(const float* __restrict__ E, float* __restrict__ e2)
{
  const int k = blockIdx.x * 256 + threadIdx.x;
  if (k >= KCODES) return;
  float s = 0.f;
  #pragma unroll 4
  for (int d = 0; d < 128; ++d) { float v = E[(size_t)k * 128 + d]; s += v * v; }
  e2[k] = s;
}

__global__ void zero_counts(int* counts)
{
  const int i = blockIdx.x * 256 + threadIdx.x;
  if (i < KCODES) counts[i] = 0;
}

__global__ void gelu_ew(float* __restrict__ p, int n)
{
  const int i = blockIdx.x * 256 + threadIdx.x;
  if (i < n) { float v = p[i]; p[i] = 0.5f * v * (1.f + erff(v * 0.70710678118654752f)); }
}

__global__ void gemm_n2(const float* __restrict__ T, const float* __restrict__ W6,
                        const float* __restrict__ b6, float* __restrict__ V, int M)
{
  const int r = blockIdx.x * 256 + threadIdx.x;
  if (r >= M) return;
  float a0 = b6[0], a1 = b6[1];
  #pragma unroll 4
  for (int d = 0; d < 128; ++d) {
    float t = T[(size_t)r * 128 + d];
    a0 = fmaf(t, W6[d * 2 + 0], a0);
    a1 = fmaf(t, W6[d * 2 + 1], a1);
  }
  V[r * 2 + 0] = a0; V[r * 2 + 1] = a1;
}

__global__ void vel_gather(const int* __restrict__ idx, const float* __restrict__ V,
                           float* __restrict__ out)
{
  const int b = blockIdx.x * 256 + threadIdx.x;
  if (b >= B_ROWS) return;
  const int k = idx[b];
  out[b * 2 + 0] = V[k * 2 + 0];
  out[b * 2 + 1] = V[k * 2 + 1];
}

__global__ __launch_bounds__(256)
void stats_kernel(const float* __restrict__ cpart, const int* __restrict__ counts,
                  float* __restrict__ outs)
{
  __shared__ float sh[256];
  __shared__ float sh2[256];
  __shared__ int shi[256];
  const int t = threadIdx.x;
  float cs = 0.f;
  for (int i = t; i < 4096; i += 256) cs += cpart[i];
  float h = 0.f; int act = 0;
  for (int k = t; k < KCODES; k += 256) {
    float avg = counts[k] * (1.0f / 32768.0f);
    h += avg * logf(avg + 1e-10f);
    act += (avg > 0.001f) ? 1 : 0;
  }
  sh[t] = cs; sh2[t] = h; shi[t] = act;
  __syncthreads();
  for (int s = 128; s; s >>= 1) {
    if (t < s) { sh[t] += sh[t + s]; sh2[t] += sh2[t + s]; shi[t] += shi[t + s]; }
    __syncthreads();
  }
  if (t == 0) {
    outs[0] = 0.25f * sh[0] / (32768.0f * 128.0f);
    outs[1] = expf(-sh2[0]);
    outs[2] = (float)shi[0];
  }
}

extern "C" void kernel_launch(void* const* d_in, const int* in_sizes, int n_in,
                              void* d_out, int out_size, void* d_ws, size_t ws_size,
                              hipStream_t stream)
{
  const float* x   = (const float*)d_in[0];
  const float* W1  = (const float*)d_in[1];
  const float* b1  = (const float*)d_in[2];
  const float* g1  = (const float*)d_in[3];
  const float* be1 = (const float*)d_in[4];
  const float* W2  = (const float*)d_in[5];
  const float* b2  = (const float*)d_in[6];
  const float* g2  = (const float*)d_in[7];
  const float* be2 = (const float*)d_in[8];
  const float* W3  = (const float*)d_in[9];
  const float* b3  = (const float*)d_in[10];
  const float* emb = (const float*)d_in[11];
  const float* W4  = (const float*)d_in[12];
  const float* b4  = (const float*)d_in[13];
  const float* g3  = (const float*)d_in[14];
  const float* be3 = (const float*)d_in[15];
  const float* W5  = (const float*)d_in[16];
  const float* b5  = (const float*)d_in[17];
  const float* W6  = (const float*)d_in[18];
  const float* b6  = (const float*)d_in[19];

  float* out = (float*)d_out;
  float* o_vel  = out;                                   // [B,2]
  float* o_ze   = out + 65536;                           // [B,128]
  float* o_zq   = out + 65536 + B_ROWS * 128;            // [B,128]
  float* o_idx  = out + 65536 + 2 * B_ROWS * 128;        // [B] (as float)
  float* o_scal = o_idx + B_ROWS;                        // 3 scalars

  float* ws = (float*)d_ws;
  float* h1f   = ws;                        // [B,512] f32 -> in-place split halves
  float* pval  = ws;                        // [B,16]
  int*   pidx  = (int*)(ws + 524288);       // [B,16]
  float* t1f   = ws + 1048576;              // [4096,256] f32 -> in-place split
  float* t2    = ws + 2097152;              // [4096,128]
  float* vv    = ws + 2621440;              // [4096,2]
  float* h2f   = ws + 16777216;             // [B,256] f32 -> in-place split
  float* e2    = ws + 25165824;             // [4096]
  int*   ind   = (int*)(ws + 25169920);     // [B]
  int*   cnt   = (int*)(ws + 25202688);     // [4096]
  float* cpart = ws + 25206784;             // [4096]
  _Float16* hb  = (_Float16*)(ws + 25210880);
  _Float16* E1  = hb;                       // 4096*128
  _Float16* E2  = E1 + 524288;
  _Float16* W1a = E2 + 524288;              // [512][1440]
  _Float16* W1b = W1a + 737280;
  _Float16* W2a = W1b + 737280;             // [256][512]
  _Float16* W2b = W2a + 131072;
  _Float16* W3a = W2b + 131072;             // [128][256]
  _Float16* W3b = W3a + 32768;
  _Float16* W4a = W3b + 32768;              // [256][128]
  _Float16* W4b = W4a + 32768;
  _Float16* W5a = W4b + 32768;              // [128][256]
  _Float16* W5b = W5a + 32768;

  // 1. init + weight prep
  zero_counts<<<16, 256, 0, stream>>>(cnt);
  e2_kernel<<<16, 256, 0, stream>>>(emb, e2);
  prep_emb<<<2048, 256, 0, stream>>>(emb, E1, E2);
  prep_wT<<<2880, 256, 0, stream>>>(W1, W1a, W1b, 1420, 512, 9, 511, 1440);
  prep_wT<<<512, 256, 0, stream>>>(W2, W2a, W2b, 512, 256, 8, 255, 512);
  prep_wT<<<128, 256, 0, stream>>>(W3, W3a, W3b, 256, 128, 7, 127, 256);
  prep_wT<<<128, 256, 0, stream>>>(W4, W4a, W4b, 128, 256, 8, 255, 128);
  prep_wT<<<128, 256, 0, stream>>>(W5, W5a, W5b, 256, 128, 7, 127, 256);

  // 2. encoder (in-kernel split for GEMM1; pre-split activations after LNs)
  hgemm<true><<<8 * 256, 256, 0, stream>>>(x, nullptr, nullptr, 0,
      W1a, W1b, b1, h1f, B_ROWS, 512, 1420, 1440, 8);
  ln_gelu_split<<<B_ROWS, 256, 0, stream>>>(h1f, g1, be1, 512);
  hgemm<false><<<4 * 256, 256, 0, stream>>>(nullptr,
      (const _Float16*)h1f, (const _Float16*)h1f + 512, 1024,
      W2a, W2b, b2, h2f, B_ROWS, 256, 512, 512, 4);
  ln_gelu_split<<<B_ROWS, 256, 0, stream>>>(h2f, g2, be2, 256);
  hgemm<false><<<2 * 256, 256, 0, stream>>>(nullptr,
      (const _Float16*)h2f, (const _Float16*)h2f + 256, 512,
      W3a, W3b, b3, o_ze, B_ROWS, 128, 256, 256, 2);

  // 3. VQ
  vq_mfma<<<2048, 256, 0, stream>>>(o_ze, E1, E2, e2, pval, pidx);
  vq_reduce<<<128, 256, 0, stream>>>(pval, pidx, ind, o_idx, cnt);
  gather_commit<<<4096, 256, 0, stream>>>(ind, emb, o_ze, o_zq, cpart);

  // 4. decoder on the 4096 distinct codes, then gather
  hgemm<false><<<4 * 32, 256, 0, stream>>>(nullptr, E1, E2, 128,
      W4a, W4b, b4, t1f, KCODES, 256, 128, 128, 4);
  ln_gelu_split<<<KCODES, 256, 0, stream>>>(t1f, g3, be3, 256);
  hgemm<false><<<2 * 32, 256, 0, stream>>>(nullptr,
      (const _Float16*)t1f, (const _Float16*)t1f + 256, 512,
      W5a, W5b, b5, t2, KCODES, 128, 256, 256, 2);
  gelu_ew<<<(KCODES * 128 + 255) / 256, 256, 0, stream>>>(t2, KCODES * 128);
  gemm_n2<<<(KCODES + 255) / 256, 256, 0, stream>>>(t2, W6, b6, vv, KCODES);
  vel_gather<<<128, 256, 0, stream>>>(ind, vv, o_vel);

  // 5. scalars
  stats_kernel<<<1, 256, 0, stream>>>(cpart, cnt, o_scal);
}

// Round 12
// 799.686 us; speedup vs baseline: 1.2183x; 1.2183x over previous
//
#include <hip/hip_runtime.h>

#define B_ROWS 32768
#define KCODES 4096

typedef float f32x4 __attribute__((ext_vector_type(4)));
typedef _Float16 f16x8 __attribute__((ext_vector_type(8)));
typedef _Float16 f16x4 __attribute__((ext_vector_type(4)));

struct Split { _Float16 h, m; };

// split f32 -> fp16 head + fp16 scaled residual (residual x256 stays normal;
// C = hi + mid/256 recombines to f32-grade accuracy)
__device__ __forceinline__ Split split2(float v)
{
  Split s;
  s.h = (_Float16)v;
  s.m = (_Float16)((v - (float)s.h) * 256.f);
  return s;
}

__device__ __forceinline__ float gelu_exact(float v)
{
  return 0.5f * v * (1.f + erff(v * 0.70710678118654752f));
}

// ---------------------------------------------------------------------------
// fp16-split MFMA GEMM, T14 1-DEEP register prefetch (round-10 structure —
// the 2-deep variant spilled: WRITE_SIZE 65->340 MB, GEMM1 225->430 us):
//   step t: lstore(t) ; barrier ; issue gload(t+1) ; MFMA(t) ; barrier
// Block tile 128x64, 4 waves of 64x32, BK=32, single-buffer LDS (30KB).
// XCD swizzle: flat -> xcd=flat&7, s=flat>>3, nb=s%nbx, mb=(s/nbx)*8+xcd.
// SPLITA=true : A f32 [M][K], split in the write phase (K-tail guarded).
// SPLITA=false: A pre-split fp16 pair, row stride Astr halves.
// GELU=true   : exact GELU applied in epilogue (fuses gelu_ew for GEMM5).
// hi += A1B1 ; mid += A1*B2s + A2s*B1 ; C = hi + mid*2^-8 + bias.
// ---------------------------------------------------------------------------
template<bool SPLITA, bool GELU>
__global__ __launch_bounds__(256, 3)
void hgemm(const float* __restrict__ Af, const _Float16* __restrict__ Ah,
           const _Float16* __restrict__ Am, int Astr,
           const _Float16* __restrict__ Bh, const _Float16* __restrict__ Bm,
           const float* __restrict__ bias, float* __restrict__ C,
           int M, int N, int K, int Kp, int nbx)
{
  __shared__ _Float16 As1[128 * 40];
  __shared__ _Float16 As2[128 * 40];
  __shared__ _Float16 Bs1[64 * 40];
  __shared__ _Float16 Bs2[64 * 40];

  const int flat = blockIdx.x;
  const int s_   = flat >> 3;
  const int mb   = (s_ / nbx) * 8 + (flat & 7);
  const int nb   = s_ % nbx;
  const int m0   = mb * 128;
  const int n0   = nb * 64;

  const int tid  = threadIdx.x;
  const int lane = tid & 63;
  const int wid  = tid >> 6;
  const int l15  = lane & 15;
  const int lg   = lane >> 4;
  const int wm   = (wid >> 1) * 64;
  const int wn   = (wid & 1) * 32;

  f32x4 hi[4][2], mid[4][2];
  #pragma unroll
  for (int i = 0; i < 4; ++i)
    #pragma unroll
    for (int j = 0; j < 2; ++j) { hi[i][j] = (f32x4)0.f; mid[i][j] = (f32x4)0.f; }

  const int far = tid >> 2;           // f32-A stage: row 0..63 (+64)
  const int fak = (tid & 3) << 3;     // 0,8,16,24
  const int sar = tid >> 1;           // pre-split A stage: row 0..127
  const int sak = (tid & 1) << 4;     // 0/16 halves
  const int sbn = tid >> 2;           // B stage: 0..63
  const int sbk = (tid & 3) << 3;     // 0,8,16,24 halves

  // 1-deep staging registers (tile in flight)
  float4 va[2][2];
  uint4 ra0, ra1, ra2, ra3;
  uint4 rb0, rb1;

  auto gload = [&](int k0) {
    if (SPLITA) {
      #pragma unroll
      for (int p = 0; p < 2; ++p) {
        const int r = far + (p << 6);
        const int c = k0 + fak;
        const float* src = Af + (size_t)(m0 + r) * K + c;
        va[p][0] = (c < K)     ? *reinterpret_cast<const float4*>(src)
                               : make_float4(0.f, 0.f, 0.f, 0.f);
        va[p][1] = (c + 4 < K) ? *reinterpret_cast<const float4*>(src + 4)
                               : make_float4(0.f, 0.f, 0.f, 0.f);
      }
    } else {
      const size_t gA = (size_t)(m0 + sar) * Astr + k0 + sak;
      ra0 = *reinterpret_cast<const uint4*>(Ah + gA);
      ra1 = *reinterpret_cast<const uint4*>(Ah + gA + 8);
      ra2 = *reinterpret_cast<const uint4*>(Am + gA);
      ra3 = *reinterpret_cast<const uint4*>(Am + gA + 8);
    }
    const size_t gB = (size_t)(n0 + sbn) * Kp + k0 + sbk;
    rb0 = *reinterpret_cast<const uint4*>(Bh + gB);
    rb1 = *reinterpret_cast<const uint4*>(Bm + gB);
  };

  auto lstore = [&]() {
    if (SPLITA) {
      #pragma unroll
      for (int p = 0; p < 2; ++p) {
        const int r = far + (p << 6);
        const Split s0 = split2(va[p][0].x), s1 = split2(va[p][0].y),
                    s2 = split2(va[p][0].z), s3 = split2(va[p][0].w);
        const Split s4 = split2(va[p][1].x), s5 = split2(va[p][1].y),
                    s6 = split2(va[p][1].z), s7 = split2(va[p][1].w);
        f16x8 h, m;
        h[0]=s0.h; h[1]=s1.h; h[2]=s2.h; h[3]=s3.h; h[4]=s4.h; h[5]=s5.h; h[6]=s6.h; h[7]=s7.h;
        m[0]=s0.m; m[1]=s1.m; m[2]=s2.m; m[3]=s3.m; m[4]=s4.m; m[5]=s5.m; m[6]=s6.m; m[7]=s7.m;
        *reinterpret_cast<f16x8*>(&As1[r * 40 + fak]) = h;
        *reinterpret_cast<f16x8*>(&As2[r * 40 + fak]) = m;
      }
    } else {
      const int lA = sar * 40 + sak;
      *reinterpret_cast<uint4*>(&As1[lA])     = ra0;
      *reinterpret_cast<uint4*>(&As1[lA + 8]) = ra1;
      *reinterpret_cast<uint4*>(&As2[lA])     = ra2;
      *reinterpret_cast<uint4*>(&As2[lA + 8]) = ra3;
    }
    const int lB = sbn * 40 + sbk;
    *reinterpret_cast<uint4*>(&Bs1[lB]) = rb0;
    *reinterpret_cast<uint4*>(&Bs2[lB]) = rb1;
  };

  const int nk = Kp >> 5;
  gload(0);
  #pragma unroll 1
  for (int kt = 0; kt < nk; ++kt) {
    lstore();
    __syncthreads();
    if (kt + 1 < nk) gload((kt + 1) << 5);   // latency hides under MFMA below

    f16x8 a1[4], b[2];
    #pragma unroll
    for (int i = 0; i < 4; ++i)
      a1[i] = *reinterpret_cast<const f16x8*>(&As1[(wm + i * 16 + l15) * 40 + 8 * lg]);
    #pragma unroll
    for (int j = 0; j < 2; ++j)
      b[j] = *reinterpret_cast<const f16x8*>(&Bs1[(wn + j * 16 + l15) * 40 + 8 * lg]);
    #pragma unroll
    for (int i = 0; i < 4; ++i)
      #pragma unroll
      for (int j = 0; j < 2; ++j)
        hi[i][j] = __builtin_amdgcn_mfma_f32_16x16x32_f16(a1[i], b[j], hi[i][j], 0, 0, 0);
    #pragma unroll
    for (int i = 0; i < 4; ++i) {
      const f16x8 a2 = *reinterpret_cast<const f16x8*>(&As2[(wm + i * 16 + l15) * 40 + 8 * lg]);
      #pragma unroll
      for (int j = 0; j < 2; ++j)
        mid[i][j] = __builtin_amdgcn_mfma_f32_16x16x32_f16(a2, b[j], mid[i][j], 0, 0, 0);
    }
    #pragma unroll
    for (int j = 0; j < 2; ++j)
      b[j] = *reinterpret_cast<const f16x8*>(&Bs2[(wn + j * 16 + l15) * 40 + 8 * lg]);
    #pragma unroll
    for (int i = 0; i < 4; ++i)
      #pragma unroll
      for (int j = 0; j < 2; ++j)
        mid[i][j] = __builtin_amdgcn_mfma_f32_16x16x32_f16(a1[i], b[j], mid[i][j], 0, 0, 0);
    __syncthreads();
  }

  // epilogue: D row = 4*lg + r, col = l15 (m89-verified layout)
  #pragma unroll
  for (int i = 0; i < 4; ++i)
    #pragma unroll
    for (int j = 0; j < 2; ++j) {
      const int col = n0 + wn + j * 16 + l15;
      const float bs = bias[col];
      #pragma unroll
      for (int r = 0; r < 4; ++r) {
        const int row = m0 + wm + i * 16 + 4 * lg + r;
        float v = hi[i][j][r] + 0.00390625f * mid[i][j][r] + bs;
        if (GELU) v = gelu_exact(v);
        C[(size_t)row * N + col] = v;
      }
    }
}

// ---------------------------------------------------------------------------
// Row LayerNorm + exact GELU, writing split fp16 pair IN-PLACE over the f32
// row: halves [0..Wd) = head, [Wd..2Wd) = scaled residual. One block per row.
// ---------------------------------------------------------------------------
__global__ __launch_bounds__(256)
void ln_gelu_split(float* __restrict__ buf, const float* __restrict__ g,
                   const float* __restrict__ be, int Wd)
{
  __shared__ float rs[4], rs2[4];
  const int row = blockIdx.x;
  const int tid = threadIdx.x;
  float* x = buf + (size_t)row * Wd;
  const float v0 = x[tid];
  const float v1 = (Wd > 256) ? x[tid + 256] : 0.f;
  float s = v0 + v1, s2 = v0 * v0 + v1 * v1;
  #pragma unroll
  for (int m = 32; m; m >>= 1) { s += __shfl_down(s, m); s2 += __shfl_down(s2, m); }
  const int ln = tid & 63, wv = tid >> 6;
  if (ln == 0) { rs[wv] = s; rs2[wv] = s2; }
  __syncthreads();
  if (tid == 0) {
    const float S = rs[0] + rs[1] + rs[2] + rs[3];
    const float S2 = rs2[0] + rs2[1] + rs2[2] + rs2[3];
    const float mean = S / Wd;
    const float var = S2 / Wd - mean * mean;
    rs[0] = mean; rs2[0] = 1.0f / sqrtf(var + 1e-5f);
  }
  __syncthreads();
  const float mean = rs[0], inv = rs2[0];
  float y0 = (v0 - mean) * inv * g[tid] + be[tid];
  y0 = gelu_exact(y0);
  float y1 = 0.f;
  if (Wd > 256) {
    y1 = (v1 - mean) * inv * g[tid + 256] + be[tid + 256];
    y1 = gelu_exact(y1);
  }
  _Float16* hb = reinterpret_cast<_Float16*>(x);
  const Split s0 = split2(y0);
  hb[tid] = s0.h; hb[Wd + tid] = s0.m;
  if (Wd > 256) {
    const Split s1 = split2(y1);
    hb[tid + 256] = s1.h; hb[Wd + tid + 256] = s1.m;
  }
}

// ---------------------------------------------------------------------------
// VQ argmin (round-10 structure, passed): Z resident in LDS; flattened 32
// steps (8 chunks x 4 k-tiles); per step: E-write(t) -> barrier -> issue
// E-load(t+1) -> MFMA(t) -> barrier. E loads are L2-resident (1-deep covers).
// Grid 2048, XCD swizzle.
// ---------------------------------------------------------------------------
__global__ __launch_bounds__(256)
void vq_mfma(const float* __restrict__ Z, const _Float16* __restrict__ E1,
             const _Float16* __restrict__ E2, const float* __restrict__ e2,
             float* __restrict__ pval, int* __restrict__ pidx)
{
  __shared__ _Float16 Zs1[64 * 136];
  __shared__ _Float16 Zs2[64 * 136];
  __shared__ _Float16 Es1[128 * 40];
  __shared__ _Float16 Es2[128 * 40];

  const int flat = blockIdx.x;
  const int s_   = flat >> 3;
  const int mb   = (s_ >> 2) * 8 + (flat & 7);
  const int split = s_ & 3;
  const int m0   = mb * 64;

  const int tid  = threadIdx.x;
  const int lane = tid & 63;
  const int wid  = tid >> 6;
  const int l15  = lane & 15;
  const int lg   = lane >> 4;
  const int wn   = wid * 32;

  {
    const int zr = tid >> 2;
    #pragma unroll
    for (int q = 0; q < 8; ++q) {
      const int kk = ((tid & 3) << 2) + (q << 4);
      float4 v = *reinterpret_cast<const float4*>(Z + (size_t)(m0 + zr) * 128 + kk);
      const Split sx = split2(v.x), sy = split2(v.y), sz = split2(v.z), sw = split2(v.w);
      f16x4 h, m;
      h[0] = sx.h; h[1] = sy.h; h[2] = sz.h; h[3] = sw.h;
      m[0] = sx.m; m[1] = sy.m; m[2] = sz.m; m[3] = sw.m;
      *reinterpret_cast<f16x4*>(&Zs1[zr * 136 + kk]) = h;
      *reinterpret_cast<f16x4*>(&Zs2[zr * 136 + kk]) = m;
    }
  }

  float bv[16];
  int   bi[16];
  #pragma unroll
  for (int s = 0; s < 16; ++s) { bv[s] = 3.4e38f; bi[s] = 0x7fffffff; }

  const int sbn = tid >> 1;
  const int sbk = (tid & 1) << 4;
  const int lb  = sbn * 40 + sbk;

  uint4 re0, re1, re2, re3;
  auto eload = [&](int t) {                 // t = ch*4 + kt
    const int n0 = split * 1024 + (t >> 2) * 128;
    const int k0 = (t & 3) << 5;
    const size_t gb = (size_t)(n0 + sbn) * 128 + k0 + sbk;
    re0 = *reinterpret_cast<const uint4*>(E1 + gb);
    re1 = *reinterpret_cast<const uint4*>(E1 + gb + 8);
    re2 = *reinterpret_cast<const uint4*>(E2 + gb);
    re3 = *reinterpret_cast<const uint4*>(E2 + gb + 8);
  };

  f32x4 hi[4][2], mid[4][2];

  eload(0);
  #pragma unroll 1
  for (int t = 0; t < 32; ++t) {
    if ((t & 3) == 0) {
      #pragma unroll
      for (int i = 0; i < 4; ++i)
        #pragma unroll
        for (int j = 0; j < 2; ++j) { hi[i][j] = (f32x4)0.f; mid[i][j] = (f32x4)0.f; }
    }
    *reinterpret_cast<uint4*>(&Es1[lb])     = re0;
    *reinterpret_cast<uint4*>(&Es1[lb + 8]) = re1;
    *reinterpret_cast<uint4*>(&Es2[lb])     = re2;
    *reinterpret_cast<uint4*>(&Es2[lb + 8]) = re3;
    __syncthreads();
    if (t + 1 < 32) eload(t + 1);

    const int k0 = (t & 3) << 5;
    f16x8 a1[4], b[2];
    #pragma unroll
    for (int i = 0; i < 4; ++i)
      a1[i] = *reinterpret_cast<const f16x8*>(&Zs1[(i * 16 + l15) * 136 + k0 + 8 * lg]);
    #pragma unroll
    for (int j = 0; j < 2; ++j)
      b[j] = *reinterpret_cast<const f16x8*>(&Es1[(wn + j * 16 + l15) * 40 + 8 * lg]);
    #pragma unroll
    for (int i = 0; i < 4; ++i)
      #pragma unroll
      for (int j = 0; j < 2; ++j)
        hi[i][j] = __builtin_amdgcn_mfma_f32_16x16x32_f16(a1[i], b[j], hi[i][j], 0, 0, 0);
    #pragma unroll
    for (int i = 0; i < 4; ++i) {
      const f16x8 a2 = *reinterpret_cast<const f16x8*>(&Zs2[(i * 16 + l15) * 136 + k0 + 8 * lg]);
      #pragma unroll
      for (int j = 0; j < 2; ++j)
        mid[i][j] = __builtin_amdgcn_mfma_f32_16x16x32_f16(a2, b[j], mid[i][j], 0, 0, 0);
    }
    #pragma unroll
    for (int j = 0; j < 2; ++j)
      b[j] = *reinterpret_cast<const f16x8*>(&Es2[(wn + j * 16 + l15) * 40 + 8 * lg]);
    #pragma unroll
    for (int i = 0; i < 4; ++i)
      #pragma unroll
      for (int j = 0; j < 2; ++j)
        mid[i][j] = __builtin_amdgcn_mfma_f32_16x16x32_f16(a1[i], b[j], mid[i][j], 0, 0, 0);

    if ((t & 3) == 3) {
      const int n0 = split * 1024 + (t >> 2) * 128;
      #pragma unroll
      for (int j = 0; j < 2; ++j) {
        const int c = n0 + wn + j * 16 + l15;
        const float ec = e2[c];
        #pragma unroll
        for (int i = 0; i < 4; ++i)
          #pragma unroll
          for (int r = 0; r < 4; ++r) {
            const float sc = ec - 2.f * (hi[i][j][r] + 0.00390625f * mid[i][j][r]);
            if (sc < bv[i * 4 + r]) { bv[i * 4 + r] = sc; bi[i * 4 + r] = c; }
          }
      }
    }
    __syncthreads();
  }

  #pragma unroll
  for (int s = 0; s < 16; ++s) {
    float v = bv[s]; int ix = bi[s];
    #pragma unroll
    for (int m = 1; m < 16; m <<= 1) {
      const float ov = __shfl_xor(v, m);
      const int   oi = __shfl_xor(ix, m);
      if (ov < v || (ov == v && oi < ix)) { v = ov; ix = oi; }
    }
    if (l15 == 0) {
      const int row = m0 + (s >> 2) * 16 + 4 * lg + (s & 3);
      pval[(size_t)row * 16 + split * 4 + wid] = v;
      pidx[(size_t)row * 16 + split * 4 + wid] = ix;
    }
  }
}

// weight prep: W [K][N] f32 -> Bh/Bm [N][Kp] fp16 (transposed, zero-padded)
__global__ void prep_wT(const float* __restrict__ W, _Float16* __restrict__ Bh,
                        _Float16* __restrict__ Bm, int K, int N, int nshift,
                        int nmask, int Kp)
{
  const int i = blockIdx.x * 256 + threadIdx.x;
  if (i >= N * Kp) return;
  const int n = i & nmask;
  const int k = i >> nshift;
  const float v = (k < K) ? W[(size_t)k * N + n] : 0.f;
  const Split s = split2(v);
  Bh[(size_t)n * Kp + k] = s.h;
  Bm[(size_t)n * Kp + k] = s.m;
}

__global__ void prep_emb(const float* __restrict__ E, _Float16* __restrict__ E1,
                         _Float16* __restrict__ E2)
{
  const int i = blockIdx.x * 256 + threadIdx.x;
  const Split s = split2(E[i]);
  E1[i] = s.h; E2[i] = s.m;
}

__global__ void vq_reduce(const float* __restrict__ pval, const int* __restrict__ pidx,
                          int* __restrict__ idxout, float* __restrict__ idxf,
                          int* __restrict__ counts)
{
  const int b = blockIdx.x * 256 + threadIdx.x;
  if (b >= B_ROWS) return;
  float best = 3.4e38f; int bix = 0x7fffffff;
  #pragma unroll
  for (int j = 0; j < 16; ++j) {
    const float v = pval[(size_t)b * 16 + j];
    const int   ii = pidx[(size_t)b * 16 + j];
    if (v < best || (v == best && ii < bix)) { best = v; bix = ii; }
  }
  idxout[b] = bix;
  idxf[b] = (float)bix;
  atomicAdd(&counts[bix], 1);
}

__global__ __launch_bounds__(256)
void gather_commit(const int* __restrict__ idx, const float* __restrict__ E,
                   const float* __restrict__ ZE, float* __restrict__ ZQ,
                   float* __restrict__ cpart)
{
  __shared__ float red[4];
  const int b = blockIdx.x * 8 + (threadIdx.x >> 5);
  const int ch = threadIdx.x & 31;
  const int k = idx[b];
  float4 q = *reinterpret_cast<const float4*>(E + (size_t)k * 128 + ch * 4);
  float4 z = *reinterpret_cast<const float4*>(ZE + (size_t)b * 128 + ch * 4);
  *reinterpret_cast<float4*>(ZQ + (size_t)b * 128 + ch * 4) = q;
  float dx = q.x - z.x, dy = q.y - z.y, dz = q.z - z.z, dw = q.w - z.w;
  float s = dx * dx + dy * dy + dz * dz + dw * dw;
  #pragma unroll
  for (int m = 32; m; m >>= 1) s += __shfl_down(s, m);
  const int lane = threadIdx.x & 63, wv = threadIdx.x >> 6;
  if (lane == 0) red[wv] = s;
  __syncthreads();
  if (threadIdx.x == 0) cpart[blockIdx.x] = red[0] + red[1] + red[2] + red[3];
}

__global__ void e2_kernel(const float* __restrict__ E, float* __restrict__ e2)
{
  const int k = blockIdx.x * 256 + threadIdx.x;
  if (k >= KCODES) return;
  float s = 0.f;
  #pragma unroll 4
  for (int d = 0; d < 128; ++d) { float v = E[(size_t)k * 128 + d]; s += v * v; }
  e2[k] = s;
}

__global__ void zero_counts(int* counts)
{
  const int i = blockIdx.x * 256 + threadIdx.x;
  if (i < KCODES) counts[i] = 0;
}

__global__ void gemm_n2(const float* __restrict__ T, const float* __restrict__ W6,
                        const float* __restrict__ b6, float* __restrict__ V, int M)
{
  const int r = blockIdx.x * 256 + threadIdx.x;
  if (r >= M) return;
  float a0 = b6[0], a1 = b6[1];
  #pragma unroll 4
  for (int d = 0; d < 128; ++d) {
    float t = T[(size_t)r * 128 + d];
    a0 = fmaf(t, W6[d * 2 + 0], a0);
    a1 = fmaf(t, W6[d * 2 + 1], a1);
  }
  V[r * 2 + 0] = a0; V[r * 2 + 1] = a1;
}

__global__ void vel_gather(const int* __restrict__ idx, const float* __restrict__ V,
                           float* __restrict__ out)
{
  const int b = blockIdx.x * 256 + threadIdx.x;
  if (b >= B_ROWS) return;
  const int k = idx[b];
  out[b * 2 + 0] = V[k * 2 + 0];
  out[b * 2 + 1] = V[k * 2 + 1];
}

__global__ __launch_bounds__(256)
void stats_kernel(const float* __restrict__ cpart, const int* __restrict__ counts,
                  float* __restrict__ outs)
{
  __shared__ float sh[256];
  __shared__ float sh2[256];
  __shared__ int shi[256];
  const int t = threadIdx.x;
  float cs = 0.f;
  for (int i = t; i < 4096; i += 256) cs += cpart[i];
  float h = 0.f; int act = 0;
  for (int k = t; k < KCODES; k += 256) {
    float avg = counts[k] * (1.0f / 32768.0f);
    h += avg * logf(avg + 1e-10f);
    act += (avg > 0.001f) ? 1 : 0;
  }
  sh[t] = cs; sh2[t] = h; shi[t] = act;
  __syncthreads();
  for (int s = 128; s; s >>= 1) {
    if (t < s) { sh[t] += sh[t + s]; sh2[t] += sh2[t + s]; shi[t] += shi[t + s]; }
    __syncthreads();
  }
  if (t == 0) {
    outs[0] = 0.25f * sh[0] / (32768.0f * 128.0f);
    outs[1] = expf(-sh2[0]);
    outs[2] = (float)shi[0];
  }
}

extern "C" void kernel_launch(void* const* d_in, const int* in_sizes, int n_in,
                              void* d_out, int out_size, void* d_ws, size_t ws_size,
                              hipStream_t stream)
{
  const float* x   = (const float*)d_in[0];
  const float* W1  = (const float*)d_in[1];
  const float* b1  = (const float*)d_in[2];
  const float* g1  = (const float*)d_in[3];
  const float* be1 = (const float*)d_in[4];
  const float* W2  = (const float*)d_in[5];
  const float* b2  = (const float*)d_in[6];
  const float* g2  = (const float*)d_in[7];
  const float* be2 = (const float*)d_in[8];
  const float* W3  = (const float*)d_in[9];
  const float* b3  = (const float*)d_in[10];
  const float* emb = (const float*)d_in[11];
  const float* W4  = (const float*)d_in[12];
  const float* b4  = (const float*)d_in[13];
  const float* g3  = (const float*)d_in[14];
  const float* be3 = (const float*)d_in[15];
  const float* W5  = (const float*)d_in[16];
  const float* b5  = (const float*)d_in[17];
  const float* W6  = (const float*)d_in[18];
  const float* b6  = (const float*)d_in[19];

  float* out = (float*)d_out;
  float* o_vel  = out;                                   // [B,2]
  float* o_ze   = out + 65536;                           // [B,128]
  float* o_zq   = out + 65536 + B_ROWS * 128;            // [B,128]
  float* o_idx  = out + 65536 + 2 * B_ROWS * 128;        // [B] (as float)
  float* o_scal = o_idx + B_ROWS;                        // 3 scalars

  float* ws = (float*)d_ws;
  float* h1f   = ws;                        // [B,512] f32 -> in-place split halves
  float* pval  = ws;                        // [B,16]
  int*   pidx  = (int*)(ws + 524288);       // [B,16]
  float* t1f   = ws + 1048576;              // [4096,256] f32 -> in-place split
  float* t2    = ws + 2097152;              // [4096,128]
  float* vv    = ws + 2621440;              // [4096,2]
  float* h2f   = ws + 16777216;             // [B,256] f32 -> in-place split
  float* e2    = ws + 25165824;             // [4096]
  int*   ind   = (int*)(ws + 25169920);     // [B]
  int*   cnt   = (int*)(ws + 25202688);     // [4096]
  float* cpart = ws + 25206784;             // [4096]
  _Float16* hb  = (_Float16*)(ws + 25210880);
  _Float16* E1  = hb;                       // 4096*128
  _Float16* E2  = E1 + 524288;
  _Float16* W1a = E2 + 524288;              // [512][1440]
  _Float16* W1b = W1a + 737280;
  _Float16* W2a = W1b + 737280;             // [256][512]
  _Float16* W2b = W2a + 131072;
  _Float16* W3a = W2b + 131072;             // [128][256]
  _Float16* W3b = W3a + 32768;
  _Float16* W4a = W3b + 32768;              // [256][128]
  _Float16* W4b = W4a + 32768;
  _Float16* W5a = W4b + 32768;              // [128][256]
  _Float16* W5b = W5a + 32768;

  // 1. init + weight prep
  zero_counts<<<16, 256, 0, stream>>>(cnt);
  e2_kernel<<<16, 256, 0, stream>>>(emb, e2);
  prep_emb<<<2048, 256, 0, stream>>>(emb, E1, E2);
  prep_wT<<<2880, 256, 0, stream>>>(W1, W1a, W1b, 1420, 512, 9, 511, 1440);
  prep_wT<<<512, 256, 0, stream>>>(W2, W2a, W2b, 512, 256, 8, 255, 512);
  prep_wT<<<128, 256, 0, stream>>>(W3, W3a, W3b, 256, 128, 7, 127, 256);
  prep_wT<<<128, 256, 0, stream>>>(W4, W4a, W4b, 128, 256, 8, 255, 128);
  prep_wT<<<128, 256, 0, stream>>>(W5, W5a, W5b, 256, 128, 7, 127, 256);

  // 2. encoder (in-kernel split for GEMM1; pre-split activations after LNs)
  hgemm<true, false><<<8 * 256, 256, 0, stream>>>(x, nullptr, nullptr, 0,
      W1a, W1b, b1, h1f, B_ROWS, 512, 1420, 1440, 8);
  ln_gelu_split<<<B_ROWS, 256, 0, stream>>>(h1f, g1, be1, 512);
  hgemm<false, false><<<4 * 256, 256, 0, stream>>>(nullptr,
      (const _Float16*)h1f, (const _Float16*)h1f + 512, 1024,
      W2a, W2b, b2, h2f, B_ROWS, 256, 512, 512, 4);
  ln_gelu_split<<<B_ROWS, 256, 0, stream>>>(h2f, g2, be2, 256);
  hgemm<false, false><<<2 * 256, 256, 0, stream>>>(nullptr,
      (const _Float16*)h2f, (const _Float16*)h2f + 256, 512,
      W3a, W3b, b3, o_ze, B_ROWS, 128, 256, 256, 2);

  // 3. VQ
  vq_mfma<<<2048, 256, 0, stream>>>(o_ze, E1, E2, e2, pval, pidx);
  vq_reduce<<<128, 256, 0, stream>>>(pval, pidx, ind, o_idx, cnt);
  gather_commit<<<4096, 256, 0, stream>>>(ind, emb, o_ze, o_zq, cpart);

  // 4. decoder on the 4096 distinct codes (GELU fused into GEMM5 epilogue)
  hgemm<false, false><<<4 * 32, 256, 0, stream>>>(nullptr, E1, E2, 128,
      W4a, W4b, b4, t1f, KCODES, 256, 128, 128, 4);
  ln_gelu_split<<<KCODES, 256, 0, stream>>>(t1f, g3, be3, 256);
  hgemm<false, true><<<2 * 32, 256, 0, stream>>>(nullptr,
      (const _Float16*)t1f, (const _Float16*)t1f + 256, 512,
      W5a, W5b, b5, t2, KCODES, 128, 256, 256, 2);
  gemm_n2<<<(KCODES + 255) / 256, 256, 0, stream>>>(t2, W6, b6, vv, KCODES);
  vel_gather<<<128, 256, 0, stream>>>(ind, vv, o_vel);

  // 5. scalars
  stats_kernel<<<1, 256, 0, stream>>>(cpart, cnt, o_scal);
}